// Round 1
// 133.641 us; speedup vs baseline: 1.0097x; 1.0097x over previous
//
#include <hip/hip_runtime.h>

#define TICKS 10000
#define NSYN 9
#define OUT_CH 64

#define SCATTER_BLOCKS 256
#define SCATTER_THREADS 1024
#define RED_SEG 8                          // partial hists summed per reduce block
#define RED_Y (SCATTER_BLOCKS / RED_SEG)   // 32

// ---------------------------------------------------------------------------
// Stage 0: zero the 9x10000 global histogram (ws is poisoned 0xAA each call).
// ---------------------------------------------------------------------------
__global__ void zero_kernel(float* __restrict__ p, int n) {
    int i = blockIdx.x * blockDim.x + threadIdx.x;
    if (i < n) p[i] = 0.0f;
}

// ---------------------------------------------------------------------------
// Stage 1: scatter events into the 9-class histogram.
// stride==1 fast path: class = min(y,2)*3 + min(x,2). ~97% of events are
// class 8 (x>=2 && y>=2) -> LDS-private per-block histogram (40 KB).
// Flush: when a partial buffer is available (ws big enough), each block
// writes its private hist to a DISTINCT 40 KB slice with coalesced float4
// stores (no atomics at all) -- a later reduce kernel sums them. This
// removes the 2.56M same-line global atomics that serialized the old flush.
// Rare classes (~3%) go straight to global atomics (low contention).
// generic-stride path: direct 9-way global atomics.
// ---------------------------------------------------------------------------
__global__ __launch_bounds__(SCATTER_THREADS) void scatter_kernel(
    const float* __restrict__ values,
    const int*   __restrict__ ticks,
    const int*   __restrict__ xs,
    const int*   __restrict__ ys,
    const int*   __restrict__ stride_p,
    float*       __restrict__ hist,
    float*       __restrict__ partial,    // nullptr -> legacy atomic flush
    int n)
{
    __shared__ __align__(16) float lhist[TICKS];  // 40 KB: class-8 private hist
    const int stride = stride_p[0];               // wave-uniform
    const int tid = threadIdx.x;

    if (stride == 1) {
        for (int j = tid; j < TICKS; j += SCATTER_THREADS) lhist[j] = 0.0f;
        __syncthreads();

        const int n4  = n >> 2;
        const int gsz = gridDim.x * SCATTER_THREADS;
        const float4* __restrict__ v4 = (const float4*)values;
        const int4*   __restrict__ t4 = (const int4*)ticks;
        const int4*   __restrict__ x4 = (const int4*)xs;
        const int4*   __restrict__ y4 = (const int4*)ys;

        for (int i = blockIdx.x * SCATTER_THREADS + tid; i < n4; i += gsz) {
            float4 v = v4[i];
            int4   t = t4[i];
            int4   x = x4[i];
            int4   y = y4[i];

            if (x.x >= 2 && y.x >= 2) atomicAdd(&lhist[t.x], v.x);
            else atomicAdd(&hist[(min(y.x, 2) * 3 + min(x.x, 2)) * TICKS + t.x], v.x);

            if (x.y >= 2 && y.y >= 2) atomicAdd(&lhist[t.y], v.y);
            else atomicAdd(&hist[(min(y.y, 2) * 3 + min(x.y, 2)) * TICKS + t.y], v.y);

            if (x.z >= 2 && y.z >= 2) atomicAdd(&lhist[t.z], v.z);
            else atomicAdd(&hist[(min(y.z, 2) * 3 + min(x.z, 2)) * TICKS + t.z], v.z);

            if (x.w >= 2 && y.w >= 2) atomicAdd(&lhist[t.w], v.w);
            else atomicAdd(&hist[(min(y.w, 2) * 3 + min(x.w, 2)) * TICKS + t.w], v.w);
        }

        // scalar tail (n not multiple of 4): straight to global (atomic-safe)
        if (blockIdx.x == 0 && tid == 0) {
            for (int i = n4 << 2; i < n; ++i) {
                atomicAdd(&hist[(min(ys[i], 2) * 3 + min(xs[i], 2)) * TICKS + ticks[i]],
                          values[i]);
            }
        }

        __syncthreads();

        if (partial != nullptr) {
            // Contention-free flush: block-private slice, coalesced float4.
            float4* __restrict__ dst =
                (float4*)(partial + (size_t)blockIdx.x * TICKS);
            const float4* __restrict__ src = (const float4*)lhist;
            for (int j = tid; j < TICKS / 4; j += SCATTER_THREADS) dst[j] = src[j];
        } else {
            // Legacy: atomic flush, phase-staggered (ws too small for partials)
            int phase = (blockIdx.x * 157) % TICKS;
            for (int j = tid; j < TICKS; j += SCATTER_THREADS) {
                int b = j + phase;
                if (b >= TICKS) b -= TICKS;
                float v = lhist[b];
                if (v != 0.0f) atomicAdd(&hist[8 * TICKS + b], v);
            }
        }
    } else {
        const int gsz = gridDim.x * SCATTER_THREADS;
        for (int i = blockIdx.x * SCATTER_THREADS + tid; i < n; i += gsz) {
            float v = values[i];
            int   t = ticks[i];
            int   x = xs[i];
            int   y = ys[i];
            #pragma unroll
            for (int ky = 0; ky < 3; ++ky) {
                int oy = y - ky;
                if (oy < 0 || (oy % stride) != 0) continue;
                #pragma unroll
                for (int kx = 0; kx < 3; ++kx) {
                    int ox = x - kx;
                    if (ox < 0 || (ox % stride) != 0) continue;
                    atomicAdd(&hist[(ky * 3 + kx) * TICKS + t], v);
                }
            }
        }
    }
}

// ---------------------------------------------------------------------------
// Stage 1b: sum the 256 per-block class-8 partial hists into hist[8].
// grid = (ceil(2500/256), 32): block y sums 8 partials; 32 atomics/address
// total (vs 256 same-line RMWs in the old flush). float4 columns, coalesced.
// Only runs on the stride==1 path (partials are unwritten otherwise).
// ---------------------------------------------------------------------------
__global__ __launch_bounds__(256) void reduce_kernel(
    const float* __restrict__ partial,
    const int*   __restrict__ stride_p,
    float*       __restrict__ hist)
{
    if (stride_p[0] != 1) return;
    int c = blockIdx.x * 256 + threadIdx.x;       // float4 column index
    if (c >= TICKS / 4) return;

    const float4* __restrict__ p4 = (const float4*)partial;
    const int base = blockIdx.y * RED_SEG;
    float ax = 0.f, ay = 0.f, az = 0.f, aw = 0.f;
    #pragma unroll
    for (int k = 0; k < RED_SEG; ++k) {
        float4 v = p4[(size_t)(base + k) * (TICKS / 4) + c];
        ax += v.x; ay += v.y; az += v.z; aw += v.w;
    }
    float* h = hist + 8 * TICKS + c * 4;
    atomicAdd(h + 0, ax);
    atomicAdd(h + 1, ay);
    atomicAdd(h + 2, az);
    atomicAdd(h + 3, aw);
}

// ---------------------------------------------------------------------------
// Stage 2: suffix-sum the 3x3 classes (stride==1 only) and broadcast to all
// 64 channels. Thread owns tick column t. With gridDim.y == 1 (hist aliases
// out) one thread writes every channel; reads of column t happen before any
// write to column t, so aliasing is safe.
// ---------------------------------------------------------------------------
__global__ __launch_bounds__(256) void emit_kernel(
    const float* __restrict__ hist,
    const int*   __restrict__ stride_p,
    float*       __restrict__ out)
{
    int t = blockIdx.x * blockDim.x + threadIdx.x;
    if (t >= TICKS) return;
    const int stride = stride_p[0];

    float b[NSYN];
    #pragma unroll
    for (int s = 0; s < NSYN; ++s) b[s] = hist[s * TICKS + t];

    if (stride == 1) {
        // class hist h[cy][cx] -> buf[ky][kx] = sum_{cy>=ky, cx>=kx} h[cy][cx]
        #pragma unroll
        for (int r = 0; r < 3; ++r) {
            b[r * 3 + 1] += b[r * 3 + 2];
            b[r * 3 + 0] += b[r * 3 + 1];
        }
        #pragma unroll
        for (int c = 0; c < 3; ++c) {
            b[3 + c] += b[6 + c];
            b[0 + c] += b[3 + c];
        }
    }

    for (int c = blockIdx.y; c < OUT_CH; c += gridDim.y) {
        #pragma unroll
        for (int s = 0; s < NSYN; ++s) {
            __builtin_nontemporal_store(b[s], &out[(c * NSYN + s) * TICKS + t]);
        }
    }
}

// ---------------------------------------------------------------------------
extern "C" void kernel_launch(void* const* d_in, const int* in_sizes, int n_in,
                              void* d_out, int out_size, void* d_ws, size_t ws_size,
                              hipStream_t stream) {
    const float* values   = (const float*)d_in[0];
    const int*   ticks    = (const int*)  d_in[1];
    const int*   xs       = (const int*)  d_in[2];
    const int*   ys       = (const int*)  d_in[3];
    const int*   stride_p = (const int*)  d_in[4];
    float*       out      = (float*)      d_out;
    const int n = in_sizes[0];

    const size_t hist_bytes = (size_t)NSYN * TICKS * sizeof(float);
    const size_t part_bytes = (size_t)SCATTER_BLOCKS * TICKS * sizeof(float);

    float* hist;
    float* partial = nullptr;
    bool hist_in_out;
    if (ws_size >= hist_bytes + part_bytes) {
        hist = (float*)d_ws;
        partial = (float*)d_ws + (size_t)NSYN * TICKS;  // 360000 B in, 16B-aligned
        hist_in_out = false;
    } else if (ws_size >= hist_bytes) {
        hist = (float*)d_ws;
        hist_in_out = false;
    } else {
        hist = out;               // reuse channel-0 region of output as scratch
        hist_in_out = true;
    }

    // Stage 0: zero hist
    {
        int nh = NSYN * TICKS;
        zero_kernel<<<(nh + 255) / 256, 256, 0, stream>>>(hist, nh);
    }

    // Stage 1: scatter — 256 blocks x 1024 threads, 1 block/CU (40 KB LDS)
    scatter_kernel<<<SCATTER_BLOCKS, SCATTER_THREADS, 0, stream>>>(
        values, ticks, xs, ys, stride_p, hist, partial, n);

    // Stage 1b: contention-free partial reduction into hist[8]
    if (partial != nullptr) {
        dim3 rg((TICKS / 4 + 255) / 256, RED_Y);
        reduce_kernel<<<rg, 256, 0, stream>>>(partial, stride_p, hist);
    }

    // Stage 2: suffix + 64-channel broadcast
    {
        dim3 grid((TICKS + 255) / 256, hist_in_out ? 1 : 64);
        emit_kernel<<<grid, 256, 0, stream>>>(hist, stride_p, out);
    }
}